// Round 9
// baseline (948.041 us; speedup 1.0000x reference)
//
#include <hip/hip_runtime.h>

#define TPB 256

typedef __attribute__((ext_vector_type(8))) short s8v;
typedef __attribute__((ext_vector_type(4))) float f4v;
typedef __bf16 bf16x8v __attribute__((ext_vector_type(8)));

__device__ inline short f2b(float f) {
    unsigned u = __builtin_bit_cast(unsigned, f);
    unsigned r = (u + 0x7FFF + ((u >> 16) & 1)) >> 16;
    return (short)r;
}
__device__ inline float b2f(short s) {
    unsigned u = ((unsigned)(unsigned short)s) << 16;
    return __builtin_bit_cast(float, u);
}
__device__ inline f4v mfma16(s8v a, s8v b, f4v c) {
    return __builtin_amdgcn_mfma_f32_16x16x32_bf16(
        __builtin_bit_cast(bf16x8v, a), __builtin_bit_cast(bf16x8v, b), c, 0, 0, 0);
}

// ---------------------------------------------------------------------------
// prep: weight transpose (OIHW/IOHW fp32 -> fragment-packed bf16) + codebook
// split (hi/lo bf16 fragment-packed + |c|^2), one fused launch.
// ---------------------------------------------------------------------------
struct WtDesc { const float* src; int CO, CI, T, iohw, start; };
struct WtArgs { WtDesc d[13]; int total; };

__global__ __launch_bounds__(256)
void prep_k(WtArgs a, short* dst, const float* __restrict__ cb,
            short* __restrict__ cbh, short* __restrict__ cbl, float* __restrict__ cbsq)
{
    const int bx = blockIdx.x;
    const int tid = threadIdx.x;
    if (bx >= 2560) {
        int c = (bx - 2560) * 256 + tid;              // 0..511
        const float* src = cb + (size_t)c * 64;
        const int nt = c >> 4, rl = c & 15;
        float sq = 0.f;
        for (int d = 0; d < 64; ++d) {
            float v = src[d];
            sq += v * v;
            short h = f2b(v);
            short lo = f2b(v - b2f(h));
            int kc = d >> 5, qd = (d >> 3) & 3, j = d & 7;
            int pos = ((kc * 32 + nt) << 9) + ((qd * 16 + rl) << 3) + j;
            cbh[pos] = h;
            cbl[pos] = lo;
        }
        cbsq[c] = sq;
        return;
    }
    int i = bx * 256 + tid;
    if (i >= a.total) return;
    int s = 0;
    for (int j = 1; j < 13; ++j) if (i >= a.d[j].start) s = j;
    int off = i - a.d[s].start;
    int CI = a.d[s].CI, CO = a.d[s].CO, T = a.d[s].T;
    int KC = CI >> 5, NT = CO >> 4;
    int j    = off & 7;
    int lane = (off >> 3) & 63;
    int rl = lane & 15, qd = lane >> 4;
    int blk = off >> 9;
    int nt  = blk % NT;
    int rest = blk / NT;
    int kc  = rest % KC;
    int tap = rest / KC;
    int co = nt * 16 + rl;
    int ci = kc * 32 + qd * 8 + j;
    float v = a.d[s].iohw ? a.d[s].src[(ci * CO + co) * T + tap]
                          : a.d[s].src[(co * CI + ci) * T + tap];
    dst[i] = f2b(v);
}

// ---------------------------------------------------------------------------
// conv1: x (16,1,256,256) fp32 -> h1 NHWC bf16 (16,128,128,64), k4 s2 p1.
// XCD swizzle: oh = (bx&7)*16 + bx>>3.
// ---------------------------------------------------------------------------
__global__ __launch_bounds__(256)
void conv1_k(const float* __restrict__ x, const float* __restrict__ w,
             const float* __restrict__ bias, short* __restrict__ out)
{
    __shared__ float sx[4 * 256];
    const int tid = threadIdx.x;
    const int bx = blockIdx.x;
    const int oh = ((bx & 7) << 4) | (bx >> 3);
    const int n = blockIdx.y;
    const int co = tid & 63, wv = tid >> 6;

    float wr[16];
#pragma unroll
    for (int t = 0; t < 16; ++t) wr[t] = w[co * 16 + t];
    const float b = bias[co];

    const float* xp = x + (size_t)n * 65536;
    for (int e = tid; e < 1024; e += 256) {
        int kh = e >> 8, col = e & 255;
        int ih = oh * 2 - 1 + kh;
        sx[e] = ((unsigned)ih < 256u) ? xp[ih * 256 + col] : 0.f;
    }
    __syncthreads();

    short* op = out + (((size_t)n * 128 + oh) * 128) * 64 + co;
#pragma unroll 4
    for (int i = 0; i < 32; ++i) {
        int ow = wv * 32 + i;
        int iwb = ow * 2 - 1;
        float acc = b;
#pragma unroll
        for (int kh = 0; kh < 4; ++kh) {
#pragma unroll
            for (int kw = 0; kw < 4; ++kw) {
                int iw = iwb + kw;
                float v = ((unsigned)iw < 256u) ? sx[kh * 256 + iw] : 0.f;
                acc = fmaf(v, wr[kh * 4 + kw], acc);
            }
        }
        op[(size_t)ow * 64] = f2b(fmaxf(acc, 0.f));
    }
}

// ---------------------------------------------------------------------------
// 3x3 s1 p1 MFMA conv, M=64, halo 3x66, packed-B from global. XCD swizzle.
// ---------------------------------------------------------------------------
template<int CI, int CO, bool RELU_IN, bool RELU_OUT, bool OUT_F32>
__global__ __launch_bounds__(256)
void pconv3s_k(const short* __restrict__ in, const short* __restrict__ wt,
               const float* __restrict__ bias, void* __restrict__ outv)
{
    constexpr int KC = CI / 32, NT = CO / 16;
    constexpr int NT2 = NT / 2;
    __shared__ short sA[3 * 66 * 40];

    const int tid = threadIdx.x;
    const int bx = blockIdx.x;
    const int oh = ((bx & 7) << 3) | (bx >> 3);
    const int n  = blockIdx.y;
    const short* inb = in + (size_t)n * 4096 * CI;
    const int w = tid >> 6, l = tid & 63, rl = l & 15, qd = l >> 4;
    const int mh = w & 1, nh = w >> 1;

    f4v acc[2][NT2];
#pragma unroll
    for (int a2 = 0; a2 < 2; ++a2)
#pragma unroll
        for (int nt = 0; nt < NT2; ++nt) acc[a2][nt] = (f4v)0.f;

    for (int kc = 0; kc < KC; ++kc) {
        __syncthreads();
        for (int e = tid; e < 792; e += 256) {
            int cell = e >> 2, kcn = e & 3;
            int hr = cell / 66, col = cell - hr * 66;
            int ih = oh - 1 + hr, iw = col - 1;
            s8v v = (s8v)0;
            if ((unsigned)ih < 64u && (unsigned)iw < 64u) {
                v = *(const s8v*)(inb + ((size_t)ih * 64 + iw) * CI + kc * 32 + kcn * 8);
                if (RELU_IN) {
#pragma unroll
                    for (int j = 0; j < 8; ++j) if (v[j] < (short)0) v[j] = 0;
                }
            }
            *(s8v*)&sA[(hr * 66 + col) * 40 + kcn * 8] = v;
        }
        __syncthreads();

#pragma unroll
        for (int tap = 0; tap < 9; ++tap) {
            const int kh = tap / 3, kw = tap % 3;
            s8v af[2];
#pragma unroll
            for (int a2 = 0; a2 < 2; ++a2)
                af[a2] = *(const s8v*)&sA[(kh * 66 + mh * 32 + a2 * 16 + rl + kw) * 40 + qd * 8];
            const short* wb = wt + (((size_t)(tap * KC + kc) * NT + nh * NT2) << 9) + l * 8;
#pragma unroll
            for (int nt = 0; nt < NT2; ++nt) {
                s8v b = *(const s8v*)(wb + ((size_t)nt << 9));
#pragma unroll
                for (int a2 = 0; a2 < 2; ++a2)
                    acc[a2][nt] = mfma16(af[a2], b, acc[a2][nt]);
            }
        }
    }

#pragma unroll
    for (int a2 = 0; a2 < 2; ++a2) {
#pragma unroll
        for (int rg = 0; rg < 4; ++rg) {
            int ow = mh * 32 + a2 * 16 + qd * 4 + rg;
            size_t row = (size_t)n * 4096 + (size_t)oh * 64 + ow;
#pragma unroll
            for (int nt = 0; nt < NT2; ++nt) {
                int co = nh * NT2 * 16 + nt * 16 + rl;
                float v = acc[a2][nt][rg];
                if (bias) v += bias[co];
                if (RELU_OUT) v = fmaxf(v, 0.f);
                if (OUT_F32) ((float*)outv)[row * CO + co] = v;
                else         ((short*)outv)[row * CO + co] = f2b(v);
            }
        }
    }
}

// ---------------------------------------------------------------------------
// Fused resblock, M=64: t = in + conv1x1(relu(conv3x3(relu(in)))).
// Z=0: write t (bf16). Z=1 (encoder tail): z = pw·relu(t) + pb written fp32;
// t itself is never materialized. XCD swizzle on oh.
// ---------------------------------------------------------------------------
template<int Z>
__global__ __launch_bounds__(256)
void rfuse_k(const short* __restrict__ in, const short* __restrict__ wa,
             const short* __restrict__ wb, short* __restrict__ out,
             const short* __restrict__ wz, const float* __restrict__ zb,
             float* __restrict__ zout)
{
    __shared__ short smem[8704];      // sA(7920) / sMid(2560) / sZ(8704) phases
    short* sA = smem;
    short* sMid = smem;
    short* sZ = smem;                 // [m(64)][co(128)] stride 136

    const int tid = threadIdx.x;
    const int bx = blockIdx.x;
    const int oh = ((bx & 7) << 3) | (bx >> 3);
    const int n  = blockIdx.y;
    const short* inb = in + (size_t)n * 4096 * 128;
    const int w = tid >> 6, l = tid & 63, rl = l & 15, qd = l >> 4;

    // ---- phase 1: 3x3, 128 -> 32 (relu at staging); wave w = 16 M-rows ----
    f4v acc1[2];
    acc1[0] = (f4v)0.f; acc1[1] = (f4v)0.f;

    for (int kc = 0; kc < 4; ++kc) {
        __syncthreads();
        for (int e = tid; e < 792; e += 256) {
            int cell = e >> 2, kcn = e & 3;
            int hr = cell / 66, col = cell - hr * 66;
            int ih = oh - 1 + hr, iw = col - 1;
            s8v v = (s8v)0;
            if ((unsigned)ih < 64u && (unsigned)iw < 64u) {
                v = *(const s8v*)(inb + ((size_t)ih * 64 + iw) * 128 + kc * 32 + kcn * 8);
#pragma unroll
                for (int j = 0; j < 8; ++j) if (v[j] < (short)0) v[j] = 0;
            }
            *(s8v*)&sA[(hr * 66 + col) * 40 + kcn * 8] = v;
        }
        __syncthreads();

#pragma unroll
        for (int tap = 0; tap < 9; ++tap) {
            const int kh = tap / 3, kw = tap % 3;
            s8v af = *(const s8v*)&sA[(kh * 66 + w * 16 + rl + kw) * 40 + qd * 8];
            const short* wp = wa + (((size_t)(tap * 4 + kc) * 2) << 9) + l * 8;
            acc1[0] = mfma16(af, *(const s8v*)(wp),       acc1[0]);
            acc1[1] = mfma16(af, *(const s8v*)(wp + 512), acc1[1]);
        }
    }

    // ---- phase 2: relu(mid) -> LDS (A-layout for the 1x1) ----
    __syncthreads();
#pragma unroll
    for (int nt = 0; nt < 2; ++nt)
#pragma unroll
        for (int rg = 0; rg < 4; ++rg) {
            int m  = w * 16 + qd * 4 + rg;
            int co = nt * 16 + rl;
            sMid[m * 40 + co] = f2b(fmaxf(acc1[nt][rg], 0.f));
        }
    __syncthreads();

    // ---- phase 3: 1x1, 32 -> 128 (K=32, single MFMA-K) ----
    f4v acc2[8];
#pragma unroll
    for (int nt = 0; nt < 8; ++nt) acc2[nt] = (f4v)0.f;

    s8v am = *(const s8v*)&sMid[(w * 16 + rl) * 40 + qd * 8];
#pragma unroll
    for (int nt = 0; nt < 8; ++nt) {
        s8v b = *(const s8v*)(wb + ((size_t)nt << 9) + l * 8);
        acc2[nt] = mfma16(am, b, acc2[nt]);
    }

    // ---- phase 4: residual add (re-read in, L2-hot) ----
    const size_t sp0 = (size_t)oh * 64;
    if (Z == 0) {
        short* outb = out + (size_t)n * 4096 * 128;
#pragma unroll
        for (int rg = 0; rg < 4; ++rg) {
            int m = w * 16 + qd * 4 + rg;
            size_t sp = sp0 + m;
#pragma unroll
            for (int nt = 0; nt < 8; ++nt) {
                int co = nt * 16 + rl;
                float v = acc2[nt][rg] + b2f(inb[sp * 128 + co]);
                outb[sp * 128 + co] = f2b(v);
            }
        }
    } else {
        // t = res + 1x1 result; relu; stash bf16 tile for the pw GEMM
        __syncthreads();
#pragma unroll
        for (int rg = 0; rg < 4; ++rg) {
            int m = w * 16 + qd * 4 + rg;
            size_t sp = sp0 + m;
#pragma unroll
            for (int nt = 0; nt < 8; ++nt) {
                int co = nt * 16 + rl;
                float v = acc2[nt][rg] + b2f(inb[sp * 128 + co]);
                sZ[m * 136 + co] = f2b(fmaxf(v, 0.f));
            }
        }
        __syncthreads();

        // ---- phase 5: z = pw (128 -> 64) + pb, fp32 out ----
        f4v acc3[4];
#pragma unroll
        for (int nt = 0; nt < 4; ++nt) acc3[nt] = (f4v)0.f;
        s8v am2[4];
#pragma unroll
        for (int kc = 0; kc < 4; ++kc)
            am2[kc] = *(const s8v*)&sZ[(w * 16 + rl) * 136 + kc * 32 + qd * 8];
#pragma unroll
        for (int kc = 0; kc < 4; ++kc)
#pragma unroll
            for (int nt = 0; nt < 4; ++nt) {
                s8v b = *(const s8v*)(wz + (((size_t)(kc * 4 + nt)) << 9) + l * 8);
                acc3[nt] = mfma16(am2[kc], b, acc3[nt]);
            }
        const size_t zr0 = (size_t)n * 4096 + (size_t)oh * 64;
#pragma unroll
        for (int rg = 0; rg < 4; ++rg) {
            size_t row = zr0 + w * 16 + qd * 4 + rg;
#pragma unroll
            for (int nt = 0; nt < 4; ++nt) {
                int co = nt * 16 + rl;
                zout[row * 64 + co] = acc3[nt][rg] + zb[co];
            }
        }
    }
}

// ---------------------------------------------------------------------------
// conv2: k4 s2 p1, 64 -> 128. Parity-split halo, M=64. XCD swizzle.
// ---------------------------------------------------------------------------
__global__ __launch_bounds__(256)
void pconv2_k(const short* __restrict__ in, const short* __restrict__ wt,
              const float* __restrict__ bias, short* __restrict__ out)
{
    __shared__ short sA[2 * 4 * 66 * 40];
    const int tid = threadIdx.x;
    const int bx = blockIdx.x;
    const int oh = ((bx & 7) << 3) | (bx >> 3);
    const int n = blockIdx.y;
    const short* inb = in + (size_t)n * 16384 * 64;
    const int w = tid >> 6, l = tid & 63, rl = l & 15, qd = l >> 4;
    const int mh = w & 1, nh = w >> 1;

    f4v acc[2][4];
#pragma unroll
    for (int a2 = 0; a2 < 2; ++a2)
#pragma unroll
        for (int nt = 0; nt < 4; ++nt) acc[a2][nt] = (f4v)0.f;

    for (int kc = 0; kc < 2; ++kc) {
        __syncthreads();
        for (int e = tid; e < 2112; e += 256) {
            int cell = e >> 2, kcn = e & 3;
            int par = cell / 264;
            int rem = cell - par * 264;
            int hr = rem / 66, c = rem - hr * 66;
            int iw = par ? (2 * c - 1) : (2 * c);
            int ih = oh * 2 - 1 + hr;
            s8v v = (s8v)0;
            if ((unsigned)ih < 128u && (unsigned)iw < 128u)
                v = *(const s8v*)(inb + ((size_t)ih * 128 + iw) * 64 + kc * 32 + kcn * 8);
            *(s8v*)&sA[((par * 4 + hr) * 66 + c) * 40 + kcn * 8] = v;
        }
        __syncthreads();

#pragma unroll
        for (int tap = 0; tap < 16; ++tap) {
            const int kh = tap >> 2, kw = tap & 3;
            const int par = 1 - (kw & 1), cofs = kw >> 1;
            s8v af[2];
#pragma unroll
            for (int a2 = 0; a2 < 2; ++a2) {
                int ow = mh * 32 + a2 * 16 + rl;
                af[a2] = *(const s8v*)&sA[((par * 4 + kh) * 66 + ow + cofs) * 40 + qd * 8];
            }
            const short* wb = wt + (((size_t)(tap * 2 + kc) * 8 + nh * 4) << 9) + l * 8;
#pragma unroll
            for (int nt = 0; nt < 4; ++nt) {
                s8v b = *(const s8v*)(wb + ((size_t)nt << 9));
#pragma unroll
                for (int a2 = 0; a2 < 2; ++a2)
                    acc[a2][nt] = mfma16(af[a2], b, acc[a2][nt]);
            }
        }
    }

#pragma unroll
    for (int a2 = 0; a2 < 2; ++a2) {
#pragma unroll
        for (int rg = 0; rg < 4; ++rg) {
            int ow = mh * 32 + a2 * 16 + qd * 4 + rg;
            size_t row = (size_t)n * 4096 + (size_t)oh * 64 + ow;
#pragma unroll
            for (int nt = 0; nt < 4; ++nt) {
                int co = nh * 64 + nt * 16 + rl;
                float v = acc[a2][nt][rg] + bias[co];
                out[row * 128 + co] = f2b(fmaxf(v, 0.f));
            }
        }
    }
}

// ---------------------------------------------------------------------------
// ConvT1 (k4 s2 p1, 128->64): parity conv w/ halo. XCD swizzle on q2.
// ---------------------------------------------------------------------------
__global__ __launch_bounds__(256)
void pct1_k(const short* __restrict__ in, const short* __restrict__ wt,
            const float* __restrict__ bias, short* __restrict__ out)
{
    __shared__ short sA[3 * 66 * 40];
    const int tid = threadIdx.x;
    const int bx = blockIdx.x, n = blockIdx.y;
    const int k8 = bx & 7;
    const int P  = (bx >> 3) & 1;
    const int q2 = k8 * 8 + (bx >> 4);
    const int oh0 = (q2 >> 1) * 4 + (q2 & 1);
    const int p = (oh0 + 1) & 1;
    const int ihb0 = (oh0 + 1 - p) >> 1;
    const short* inb = in + (size_t)n * 4096 * 128;
    const int w = tid >> 6, l = tid & 63, rl = l & 15, qd = l >> 4;
    const int mh = w & 1, nh = w >> 1;

    f4v acc[4][2];
#pragma unroll
    for (int a4 = 0; a4 < 4; ++a4)
#pragma unroll
        for (int nt = 0; nt < 2; ++nt) acc[a4][nt] = (f4v)0.f;

    for (int kc = 0; kc < 4; ++kc) {
        __syncthreads();
        for (int e = tid; e < 792; e += 256) {
            int cell = e >> 2, kcn = e & 3;
            int hr = cell / 66, c = cell - hr * 66;
            int ih = ihb0 - 1 + hr, iw = c - 1;
            s8v v = (s8v)0;
            if ((unsigned)ih < 64u && (unsigned)iw < 64u)
                v = *(const s8v*)(inb + ((size_t)ih * 64 + iw) * 128 + kc * 32 + kcn * 8);
            *(s8v*)&sA[(hr * 66 + c) * 40 + kcn * 8] = v;
        }
        __syncthreads();

#pragma unroll
        for (int a = 0; a < 2; ++a)
#pragma unroll
        for (int b = 0; b < 2; ++b) {
            const int kh = p + 2 * a;
            const int kw = (1 - P) + 2 * b;
            const int tap = kh * 4 + kw;
            const int hrw = mh + 1 - a;
            s8v af[4];
#pragma unroll
            for (int a4 = 0; a4 < 4; ++a4)
                af[a4] = *(const s8v*)&sA[(hrw * 66 + a4 * 16 + rl + P - b + 1) * 40 + qd * 8];
            const short* wbp = wt + (((size_t)(tap * 4 + kc) * 4 + nh * 2) << 9) + l * 8;
#pragma unroll
            for (int nt = 0; nt < 2; ++nt) {
                s8v bb = *(const s8v*)(wbp + ((size_t)nt << 9));
#pragma unroll
                for (int a4 = 0; a4 < 4; ++a4)
                    acc[a4][nt] = mfma16(af[a4], bb, acc[a4][nt]);
            }
        }
    }

#pragma unroll
    for (int a4 = 0; a4 < 4; ++a4) {
#pragma unroll
        for (int rg = 0; rg < 4; ++rg) {
            int j = a4 * 16 + qd * 4 + rg;
            int oh = oh0 + 2 * mh, ow = 2 * j + P;
            size_t pb = (((size_t)n * 128 + oh) * 128 + ow) * 64;
#pragma unroll
            for (int nt = 0; nt < 2; ++nt) {
                int co = nh * 32 + nt * 16 + rl;
                float v = acc[a4][nt][rg] + bias[co];
                out[pb + co] = f2b(fmaxf(v, 0.f));
            }
        }
    }
}

// ---------------------------------------------------------------------------
// ConvT2: quad-per-thread. Each thread computes the 2x2 output quad at
// (2i,2j) from its 9 shared input pixels. float2 coalesced stores.
// Grid (64,16): block = 4 output rows (2 quad rows), XCD-swizzled.
// ---------------------------------------------------------------------------
__global__ __launch_bounds__(256)
void convt2_k(const short* __restrict__ in, const float* __restrict__ w,
              const float* __restrict__ bias, float* __restrict__ out)
{
    __shared__ float sw[16 * 64];
    const int tid = threadIdx.x;
    for (int e = tid; e < 1024; e += 256) { int ci = e >> 4, tap = e & 15; sw[tap * 64 + ci] = w[e]; }
    __syncthreads();

    const int bx = blockIdx.x, n = blockIdx.y;
    const int qpair = ((bx & 7) << 3) | (bx >> 3);   // [0,64)
    const int i = qpair * 2 + (tid >> 7);            // quad row [0,128)
    const int j = tid & 127;                         // quad col [0,128)
    const short* inb = in + (size_t)n * 16384 * 64;
    const float b0 = bias[0];

    float acc[2][2] = {{b0, b0}, {b0, b0}};

#pragma unroll
    for (int cc = 0; cc < 8; ++cc) {
        s8v iv[3][3];
#pragma unroll
        for (int r = 0; r < 3; ++r) {
            int ih = i - 1 + r;
            bool vr = (unsigned)ih < 128u;
#pragma unroll
            for (int c3 = 0; c3 < 3; ++c3) {
                int iw = j - 1 + c3;
                iv[r][c3] = (vr && (unsigned)iw < 128u)
                    ? *(const s8v*)(inb + ((size_t)ih * 128 + iw) * 64 + cc * 8)
                    : (s8v)0;
            }
        }
#pragma unroll
        for (int e = 0; e < 8; ++e) {
            int ci = cc * 8 + e;
            float fv[3][3];
#pragma unroll
            for (int r = 0; r < 3; ++r)
#pragma unroll
                for (int c3 = 0; c3 < 3; ++c3) fv[r][c3] = b2f(iv[r][c3][e]);
#pragma unroll
            for (int dy = 0; dy < 2; ++dy)
#pragma unroll
            for (int dx = 0; dx < 2; ++dx) {
#pragma unroll
                for (int a = 0; a < 2; ++a)
#pragma unroll
                for (int b = 0; b < 2; ++b) {
                    int tap = ((1 - dy) + 2 * a) * 4 + (1 - dx) + 2 * b;
                    acc[dy][dx] = fmaf(fv[dy + 1 - a][dx + 1 - b], sw[tap * 64 + ci], acc[dy][dx]);
                }
            }
        }
    }

    float* ob = out + (size_t)n * 65536;
#pragma unroll
    for (int dy = 0; dy < 2; ++dy) {
        int oh = 2 * i + dy;
        float2 v; v.x = acc[dy][0]; v.y = acc[dy][1];
        *(float2*)&ob[(size_t)oh * 256 + 2 * j] = v;
    }
}

// ---------------------------------------------------------------------------
// VQ: MFMA distance GEMM, split-bf16, fully-coalesced; no global atomics.
// ---------------------------------------------------------------------------
__global__ __launch_bounds__(256)
void vqm_k(const float* __restrict__ z, const short* __restrict__ cbh,
           const short* __restrict__ cbl, const float* __restrict__ cbsq,
           const float* __restrict__ cb,
           float* __restrict__ quant, short* __restrict__ qb,
           int* __restrict__ idxp, float* __restrict__ errbuf)
{
    __shared__ float zs[64 * 68];
    __shared__ short scb[2][8192];
    __shared__ int sidx[64];
    __shared__ float serr[4];
    float* qc = (float*)&scb[0][0];

    const int tid = threadIdx.x;
    const int w = tid >> 6, l = tid & 63, rl = l & 15, qd = l >> 4;
    const int r0 = blockIdx.x * 64;

    for (int e = tid; e < 1024; e += 256) {
        int row = e >> 4, c4 = e & 15;
        float4 t = ((const float4*)(z + (size_t)(r0 + row) * 64))[c4];
        *(float4*)&zs[row * 68 + c4 * 4] = t;
    }
    __syncthreads();

    s8v zh[2], zl[2];
#pragma unroll
    for (int kc = 0; kc < 2; ++kc) {
        const float* zp = &zs[(w * 16 + rl) * 68 + kc * 32 + qd * 8];
        s8v hi, lo;
#pragma unroll
        for (int j = 0; j < 8; ++j) {
            float v = zp[j];
            short h = f2b(v);
            hi[j] = h;
            lo[j] = f2b(v - b2f(h));
        }
        zh[kc] = hi; zl[kc] = lo;
    }

    float best[4]; int bidx[4];
#pragma unroll
    for (int rg = 0; rg < 4; ++rg) { best[rg] = 3.4e38f; bidx[rg] = 0; }

    for (int ch = 0; ch < 4; ++ch) {
        __syncthreads();
        for (int e = tid; e < 1024; e += 256) {
            int kcL = e >> 9, rest = e & 511;
            int ntl = rest >> 6, off = rest & 63;
            int srcIdx = (kcL * 32 + ch * 8 + ntl) * 64 + off;
            *(s8v*)&scb[0][e * 8] = ((const s8v*)cbh)[srcIdx];
            *(s8v*)&scb[1][e * 8] = ((const s8v*)cbl)[srcIdx];
        }
        __syncthreads();

        float sq[8];
#pragma unroll
        for (int nt = 0; nt < 8; ++nt) sq[nt] = cbsq[ch * 128 + nt * 16 + rl];

        f4v acc[8];
#pragma unroll
        for (int nt = 0; nt < 8; ++nt) acc[nt] = (f4v)0.f;
#pragma unroll
        for (int kc = 0; kc < 2; ++kc) {
#pragma unroll
            for (int nt = 0; nt < 8; ++nt) {
                s8v bh = *(const s8v*)&scb[0][(kc * 8 + nt) * 512 + l * 8];
                s8v bl = *(const s8v*)&scb[1][(kc * 8 + nt) * 512 + l * 8];
                acc[nt] = mfma16(zh[kc], bh, acc[nt]);
                acc[nt] = mfma16(zh[kc], bl, acc[nt]);
                acc[nt] = mfma16(zl[kc], bh, acc[nt]);
            }
        }

#pragma unroll
        for (int rg = 0; rg < 4; ++rg) {
            float bd = best[rg]; int bi = bidx[rg];
#pragma unroll
            for (int nt = 0; nt < 8; ++nt) {
                float d = sq[nt] - 2.f * acc[nt][rg];
                int code = ch * 128 + nt * 16 + rl;
                if (d < bd) { bd = d; bi = code; }
            }
            best[rg] = bd; bidx[rg] = bi;
        }
    }

#pragma unroll
    for (int rg = 0; rg < 4; ++rg) {
        float bd = best[rg]; int bi = bidx[rg];
#pragma unroll
        for (int off = 1; off < 16; off <<= 1) {
            float od = __shfl_xor(bd, off, 64);
            int   oi = __shfl_xor(bi, off, 64);
            if (od < bd || (od == bd && oi < bi)) { bd = od; bi = oi; }
        }
        if (rl == 0) sidx[w * 16 + qd * 4 + rg] = bi;
    }
    __syncthreads();

    const int n = r0 >> 12, s0 = r0 & 4095;
    float err = 0.f;
#pragma unroll 4
    for (int i = 0; i < 16; ++i) {
        int rr = w * 16 + i;
        int bi = sidx[rr];
        float c = cb[(size_t)bi * 64 + l];
        float zv = zs[rr * 68 + l];
        float dd = zv - c;
        err += dd * dd;
        qb[(size_t)(r0 + rr) * 64 + l] = f2b(c);
        qc[l * 68 + rr] = c;
    }
#pragma unroll
    for (int o = 32; o; o >>= 1) err += __shfl_down(err, o, 64);
    if (l == 0) serr[w] = err;
    if (tid < 64) idxp[r0 + tid] = sidx[tid];
    __syncthreads();

#pragma unroll 4
    for (int dd = 0; dd < 16; ++dd) {
        int d = w * 16 + dd;
        quant[((size_t)(n * 64 + d)) * 4096 + s0 + l] = qc[d * 68 + l];
    }
    if (tid == 0) errbuf[blockIdx.x] = serr[0] + serr[1] + serr[2] + serr[3];
}

__global__ __launch_bounds__(1024)
void fin_k(const int* __restrict__ idxp, const float* __restrict__ errbuf,
           float* out_loss, float* out_perp)
{
    __shared__ int lc[512];
    __shared__ float red[1024];
    const int t = threadIdx.x;
    if (t < 512) lc[t] = 0;
    __syncthreads();
    for (int i = t; i < 65536; i += 1024) atomicAdd(&lc[idxp[i]], 1);
    __syncthreads();
    float v = 0.f;
    if (t < 512) {
        float avg = (float)lc[t] * (1.0f / 65536.0f);
        v = avg * logf(avg + 1e-10f);
    }
    red[t] = v;
    __syncthreads();
    for (int st = 512; st; st >>= 1) { if (t < st) red[t] += red[t + st]; __syncthreads(); }
    if (t == 0) *out_perp = expf(-red[0]);
    __syncthreads();
    red[t] = errbuf[t];
    __syncthreads();
    for (int st = 512; st; st >>= 1) { if (t < st) red[t] += red[t + st]; __syncthreads(); }
    if (t == 0) *out_loss = red[0] * (1.25f / 4194304.0f);
}

__global__ __launch_bounds__(256)
void enc_k(const int* __restrict__ idxp, float4* __restrict__ enc)
{
    int i = blockIdx.x * 256 + threadIdx.x;
    int r = i >> 7, c4 = (i & 127) * 4;
    int k = idxp[r];
    float4 v;
    v.x = (k == c4)     ? 1.f : 0.f;
    v.y = (k == c4 + 1) ? 1.f : 0.f;
    v.z = (k == c4 + 2) ? 1.f : 0.f;
    v.w = (k == c4 + 3) ? 1.f : 0.f;
    enc[i] = v;
}

// ---------------------------------------------------------------------------
extern "C" void kernel_launch(void* const* d_in, const int* in_sizes, int n_in,
                              void* d_out, int out_size, void* d_ws, size_t ws_size,
                              hipStream_t stream)
{
    const float* x    = (const float*)d_in[0];
    const float* ew1  = (const float*)d_in[1];
    const float* eb1  = (const float*)d_in[2];
    const float* ew2  = (const float*)d_in[3];
    const float* eb2  = (const float*)d_in[4];
    const float* ew3  = (const float*)d_in[5];
    const float* eb3  = (const float*)d_in[6];
    const float* er1a = (const float*)d_in[7];
    const float* er1b = (const float*)d_in[8];
    const float* er2a = (const float*)d_in[9];
    const float* er2b = (const float*)d_in[10];
    const float* pw   = (const float*)d_in[11];
    const float* pb   = (const float*)d_in[12];
    const float* cb   = (const float*)d_in[13];
    const float* dw1w = (const float*)d_in[14];
    const float* db1  = (const float*)d_in[15];
    const float* dr1a = (const float*)d_in[16];
    const float* dr1b = (const float*)d_in[17];
    const float* dr2a = (const float*)d_in[18];
    const float* dr2b = (const float*)d_in[19];
    const float* dtw1 = (const float*)d_in[20];
    const float* dtb1 = (const float*)d_in[21];
    const float* dtw2 = (const float*)d_in[22];
    const float* dtb2 = (const float*)d_in[23];

    char* wsb = (char*)d_ws;
    short* wbase = (short*)wsb;
    short* wt2   = wbase;
    short* wt3   = wbase + 131072;
    short* wr1a  = wbase + 278528;
    short* wr1b  = wbase + 315392;
    short* wr2a  = wbase + 319488;
    short* wr2b  = wbase + 356352;
    short* wpwt  = wbase + 360448;
    short* wd1   = wbase + 368640;
    short* wdr1a = wbase + 442368;
    short* wdr1b = wbase + 479232;
    short* wdr2a = wbase + 483328;
    short* wdr2b = wbase + 520192;
    short* wtt1  = wbase + 524288;

    short* h2   = (short*)(wsb + 1310720);
    short* buf  = (short*)(wsb + 18087936);
    short* qb   = (short*)(wsb + 39059456);
    float* z    = (float*)(wsb + 47448064);
    int*   idx  = (int*)  (wsb + 64225280);
    if (ws_size < (size_t)64489480) return;

    float* out    = (float*)d_out;
    float* o_loss = out;
    float* xrec   = out + 1;
    float* o_perp = out + 1048577;
    float* enc    = out + 1048578;
    float* quant  = out + 34603010;
    char*  encB = (char*)d_out + (size_t)1048580 * 4;
    short* h1  = (short*)encB;
    short* dt1 = h1 + 16777216;
    short* cbh  = (short*)(encB + ((size_t)120 << 20));
    short* cbl  = cbh + 32768;
    float* cbsq = (float*)(cbl + 32768);
    float* errbuf = (float*)(encB + ((size_t)121 << 20));

    WtArgs wa;
    wa.d[0]  = { ew2,  128,  64, 16, 0, 0      };
    wa.d[1]  = { ew3,  128, 128,  9, 0, 131072 };
    wa.d[2]  = { er1a,  32, 128,  9, 0, 278528 };
    wa.d[3]  = { er1b, 128,  32,  1, 0, 315392 };
    wa.d[4]  = { er2a,  32, 128,  9, 0, 319488 };
    wa.d[5]  = { er2b, 128,  32,  1, 0, 356352 };
    wa.d[6]  = { pw,    64, 128,  1, 0, 360448 };
    wa.d[7]  = { dw1w, 128,  64,  9, 0, 368640 };
    wa.d[8]  = { dr1a,  32, 128,  9, 0, 442368 };
    wa.d[9]  = { dr1b, 128,  32,  1, 0, 479232 };
    wa.d[10] = { dr2a,  32, 128,  9, 0, 483328 };
    wa.d[11] = { dr2b, 128,  32,  1, 0, 520192 };
    wa.d[12] = { dtw1,  64, 128, 16, 1, 524288 };
    wa.total = 655360;
    prep_k<<<dim3(2562), TPB, 0, stream>>>(wa, wbase, cb, cbh, cbl, cbsq);

    // ---- encoder ----
    conv1_k<<<dim3(128, 16), TPB, 0, stream>>>(x, ew1, eb1, h1);
    pconv2_k<<<dim3(64, 16), TPB, 0, stream>>>(h1, wt2, eb2, h2);
    pconv3s_k<128,128,false,false,false><<<dim3(64,16), TPB, 0, stream>>>(h2, wt3, eb3, buf);
    rfuse_k<0><<<dim3(64,16), TPB, 0, stream>>>(buf, wr1a, wr1b, h2, nullptr, nullptr, nullptr);
    rfuse_k<1><<<dim3(64,16), TPB, 0, stream>>>(h2,  wr2a, wr2b, nullptr, wpwt, pb, z);

    // ---- VQ ----
    vqm_k<<<dim3(1024), TPB, 0, stream>>>(z, cbh, cbl, cbsq, cb, quant, qb, idx, errbuf);
    fin_k<<<dim3(1), 1024, 0, stream>>>(idx, errbuf, o_loss, o_perp);

    // ---- decoder ----
    pconv3s_k< 64,128,false,false,false><<<dim3(64,16), TPB, 0, stream>>>(qb, wd1, db1, buf);
    rfuse_k<0><<<dim3(64,16), TPB, 0, stream>>>(buf, wdr1a, wdr1b, h2, nullptr, nullptr, nullptr);
    rfuse_k<0><<<dim3(64,16), TPB, 0, stream>>>(h2,  wdr2a, wdr2b, buf, nullptr, nullptr, nullptr);
    pct1_k<<<dim3(128, 16), TPB, 0, stream>>>(buf, wtt1, dtb1, dt1);
    convt2_k<<<dim3(64, 16), TPB, 0, stream>>>(dt1, dtw2, dtb2, xrec);

    // ---- encodings (last) ----
    enc_k<<<dim3(32768), TPB, 0, stream>>>(idx, (float4*)enc);
}

// Round 10
// 551.017 us; speedup vs baseline: 1.7205x; 1.7205x over previous
//
#include <hip/hip_runtime.h>

#define TPB 256

typedef __attribute__((ext_vector_type(8))) short s8v;
typedef __attribute__((ext_vector_type(4))) float f4v;
typedef __bf16 bf16x8v __attribute__((ext_vector_type(8)));

__device__ inline short f2b(float f) {
    unsigned u = __builtin_bit_cast(unsigned, f);
    unsigned r = (u + 0x7FFF + ((u >> 16) & 1)) >> 16;
    return (short)r;
}
__device__ inline float b2f(short s) {
    unsigned u = ((unsigned)(unsigned short)s) << 16;
    return __builtin_bit_cast(float, u);
}
__device__ inline f4v mfma16(s8v a, s8v b, f4v c) {
    return __builtin_amdgcn_mfma_f32_16x16x32_bf16(
        __builtin_bit_cast(bf16x8v, a), __builtin_bit_cast(bf16x8v, b), c, 0, 0, 0);
}

// ---------------------------------------------------------------------------
// prep: weight transpose (OIHW/IOHW fp32 -> fragment-packed bf16) + codebook
// split (hi/lo bf16 fragment-packed + |c|^2), one fused launch.
// ---------------------------------------------------------------------------
struct WtDesc { const float* src; int CO, CI, T, iohw, start; };
struct WtArgs { WtDesc d[13]; int total; };

__global__ __launch_bounds__(256)
void prep_k(WtArgs a, short* dst, const float* __restrict__ cb,
            short* __restrict__ cbh, short* __restrict__ cbl, float* __restrict__ cbsq)
{
    const int bx = blockIdx.x;
    const int tid = threadIdx.x;
    if (bx >= 2560) {
        int c = (bx - 2560) * 256 + tid;              // 0..511
        const float* src = cb + (size_t)c * 64;
        const int nt = c >> 4, rl = c & 15;
        float sq = 0.f;
        for (int d = 0; d < 64; ++d) {
            float v = src[d];
            sq += v * v;
            short h = f2b(v);
            short lo = f2b(v - b2f(h));
            int kc = d >> 5, qd = (d >> 3) & 3, j = d & 7;
            int pos = ((kc * 32 + nt) << 9) + ((qd * 16 + rl) << 3) + j;
            cbh[pos] = h;
            cbl[pos] = lo;
        }
        cbsq[c] = sq;
        return;
    }
    int i = bx * 256 + tid;
    if (i >= a.total) return;
    int s = 0;
    for (int j = 1; j < 13; ++j) if (i >= a.d[j].start) s = j;
    int off = i - a.d[s].start;
    int CI = a.d[s].CI, CO = a.d[s].CO, T = a.d[s].T;
    int KC = CI >> 5, NT = CO >> 4;
    int j    = off & 7;
    int lane = (off >> 3) & 63;
    int rl = lane & 15, qd = lane >> 4;
    int blk = off >> 9;
    int nt  = blk % NT;
    int rest = blk / NT;
    int kc  = rest % KC;
    int tap = rest / KC;
    int co = nt * 16 + rl;
    int ci = kc * 32 + qd * 8 + j;
    float v = a.d[s].iohw ? a.d[s].src[(ci * CO + co) * T + tap]
                          : a.d[s].src[(co * CI + ci) * T + tap];
    dst[i] = f2b(v);
}

// ---------------------------------------------------------------------------
// conv1: x (16,1,256,256) fp32 -> h1 NHWC bf16 (16,128,128,64), k4 s2 p1.
// XCD swizzle: oh = (bx&7)*16 + bx>>3.
// ---------------------------------------------------------------------------
__global__ __launch_bounds__(256)
void conv1_k(const float* __restrict__ x, const float* __restrict__ w,
             const float* __restrict__ bias, short* __restrict__ out)
{
    __shared__ float sx[4 * 256];
    const int tid = threadIdx.x;
    const int bx = blockIdx.x;
    const int oh = ((bx & 7) << 4) | (bx >> 3);
    const int n = blockIdx.y;
    const int co = tid & 63, wv = tid >> 6;

    float wr[16];
#pragma unroll
    for (int t = 0; t < 16; ++t) wr[t] = w[co * 16 + t];
    const float b = bias[co];

    const float* xp = x + (size_t)n * 65536;
    for (int e = tid; e < 1024; e += 256) {
        int kh = e >> 8, col = e & 255;
        int ih = oh * 2 - 1 + kh;
        sx[e] = ((unsigned)ih < 256u) ? xp[ih * 256 + col] : 0.f;
    }
    __syncthreads();

    short* op = out + (((size_t)n * 128 + oh) * 128) * 64 + co;
#pragma unroll 4
    for (int i = 0; i < 32; ++i) {
        int ow = wv * 32 + i;
        int iwb = ow * 2 - 1;
        float acc = b;
#pragma unroll
        for (int kh = 0; kh < 4; ++kh) {
#pragma unroll
            for (int kw = 0; kw < 4; ++kw) {
                int iw = iwb + kw;
                float v = ((unsigned)iw < 256u) ? sx[kh * 256 + iw] : 0.f;
                acc = fmaf(v, wr[kh * 4 + kw], acc);
            }
        }
        op[(size_t)ow * 64] = f2b(fmaxf(acc, 0.f));
    }
}

// ---------------------------------------------------------------------------
// 3x3 s1 p1 MFMA conv, M=64, halo 3x66, packed-B from global. XCD swizzle.
// ---------------------------------------------------------------------------
template<int CI, int CO, bool RELU_IN, bool RELU_OUT, bool OUT_F32>
__global__ __launch_bounds__(256)
void pconv3s_k(const short* __restrict__ in, const short* __restrict__ wt,
               const float* __restrict__ bias, void* __restrict__ outv)
{
    constexpr int KC = CI / 32, NT = CO / 16;
    constexpr int NT2 = NT / 2;
    __shared__ short sA[3 * 66 * 40];

    const int tid = threadIdx.x;
    const int bx = blockIdx.x;
    const int oh = ((bx & 7) << 3) | (bx >> 3);
    const int n  = blockIdx.y;
    const short* inb = in + (size_t)n * 4096 * CI;
    const int w = tid >> 6, l = tid & 63, rl = l & 15, qd = l >> 4;
    const int mh = w & 1, nh = w >> 1;

    f4v acc[2][NT2];
#pragma unroll
    for (int a2 = 0; a2 < 2; ++a2)
#pragma unroll
        for (int nt = 0; nt < NT2; ++nt) acc[a2][nt] = (f4v)0.f;

    for (int kc = 0; kc < KC; ++kc) {
        __syncthreads();
        for (int e = tid; e < 792; e += 256) {
            int cell = e >> 2, kcn = e & 3;
            int hr = cell / 66, col = cell - hr * 66;
            int ih = oh - 1 + hr, iw = col - 1;
            s8v v = (s8v)0;
            if ((unsigned)ih < 64u && (unsigned)iw < 64u) {
                v = *(const s8v*)(inb + ((size_t)ih * 64 + iw) * CI + kc * 32 + kcn * 8);
                if (RELU_IN) {
#pragma unroll
                    for (int j = 0; j < 8; ++j) if (v[j] < (short)0) v[j] = 0;
                }
            }
            *(s8v*)&sA[(hr * 66 + col) * 40 + kcn * 8] = v;
        }
        __syncthreads();

#pragma unroll
        for (int tap = 0; tap < 9; ++tap) {
            const int kh = tap / 3, kw = tap % 3;
            s8v af[2];
#pragma unroll
            for (int a2 = 0; a2 < 2; ++a2)
                af[a2] = *(const s8v*)&sA[(kh * 66 + mh * 32 + a2 * 16 + rl + kw) * 40 + qd * 8];
            const short* wb = wt + (((size_t)(tap * KC + kc) * NT + nh * NT2) << 9) + l * 8;
#pragma unroll
            for (int nt = 0; nt < NT2; ++nt) {
                s8v b = *(const s8v*)(wb + ((size_t)nt << 9));
#pragma unroll
                for (int a2 = 0; a2 < 2; ++a2)
                    acc[a2][nt] = mfma16(af[a2], b, acc[a2][nt]);
            }
        }
    }

#pragma unroll
    for (int a2 = 0; a2 < 2; ++a2) {
#pragma unroll
        for (int rg = 0; rg < 4; ++rg) {
            int ow = mh * 32 + a2 * 16 + qd * 4 + rg;
            size_t row = (size_t)n * 4096 + (size_t)oh * 64 + ow;
#pragma unroll
            for (int nt = 0; nt < NT2; ++nt) {
                int co = nh * NT2 * 16 + nt * 16 + rl;
                float v = acc[a2][nt][rg];
                if (bias) v += bias[co];
                if (RELU_OUT) v = fmaxf(v, 0.f);
                if (OUT_F32) ((float*)outv)[row * CO + co] = v;
                else         ((short*)outv)[row * CO + co] = f2b(v);
            }
        }
    }
}

// ---------------------------------------------------------------------------
// Fused resblock, M=64: t = in + conv1x1(relu(conv3x3(relu(in)))).
// Z=0: write t (bf16). Z=1 (encoder tail): z = pw·relu(t) + pb written fp32.
// ---------------------------------------------------------------------------
template<int Z>
__global__ __launch_bounds__(256)
void rfuse_k(const short* __restrict__ in, const short* __restrict__ wa,
             const short* __restrict__ wb, short* __restrict__ out,
             const short* __restrict__ wz, const float* __restrict__ zb,
             float* __restrict__ zout)
{
    __shared__ short smem[8704];
    short* sA = smem;
    short* sMid = smem;
    short* sZ = smem;

    const int tid = threadIdx.x;
    const int bx = blockIdx.x;
    const int oh = ((bx & 7) << 3) | (bx >> 3);
    const int n  = blockIdx.y;
    const short* inb = in + (size_t)n * 4096 * 128;
    const int w = tid >> 6, l = tid & 63, rl = l & 15, qd = l >> 4;

    f4v acc1[2];
    acc1[0] = (f4v)0.f; acc1[1] = (f4v)0.f;

    for (int kc = 0; kc < 4; ++kc) {
        __syncthreads();
        for (int e = tid; e < 792; e += 256) {
            int cell = e >> 2, kcn = e & 3;
            int hr = cell / 66, col = cell - hr * 66;
            int ih = oh - 1 + hr, iw = col - 1;
            s8v v = (s8v)0;
            if ((unsigned)ih < 64u && (unsigned)iw < 64u) {
                v = *(const s8v*)(inb + ((size_t)ih * 64 + iw) * 128 + kc * 32 + kcn * 8);
#pragma unroll
                for (int j = 0; j < 8; ++j) if (v[j] < (short)0) v[j] = 0;
            }
            *(s8v*)&sA[(hr * 66 + col) * 40 + kcn * 8] = v;
        }
        __syncthreads();

#pragma unroll
        for (int tap = 0; tap < 9; ++tap) {
            const int kh = tap / 3, kw = tap % 3;
            s8v af = *(const s8v*)&sA[(kh * 66 + w * 16 + rl + kw) * 40 + qd * 8];
            const short* wp = wa + (((size_t)(tap * 4 + kc) * 2) << 9) + l * 8;
            acc1[0] = mfma16(af, *(const s8v*)(wp),       acc1[0]);
            acc1[1] = mfma16(af, *(const s8v*)(wp + 512), acc1[1]);
        }
    }

    __syncthreads();
#pragma unroll
    for (int nt = 0; nt < 2; ++nt)
#pragma unroll
        for (int rg = 0; rg < 4; ++rg) {
            int m  = w * 16 + qd * 4 + rg;
            int co = nt * 16 + rl;
            sMid[m * 40 + co] = f2b(fmaxf(acc1[nt][rg], 0.f));
        }
    __syncthreads();

    f4v acc2[8];
#pragma unroll
    for (int nt = 0; nt < 8; ++nt) acc2[nt] = (f4v)0.f;

    s8v am = *(const s8v*)&sMid[(w * 16 + rl) * 40 + qd * 8];
#pragma unroll
    for (int nt = 0; nt < 8; ++nt) {
        s8v b = *(const s8v*)(wb + ((size_t)nt << 9) + l * 8);
        acc2[nt] = mfma16(am, b, acc2[nt]);
    }

    const size_t sp0 = (size_t)oh * 64;
    if (Z == 0) {
        short* outb = out + (size_t)n * 4096 * 128;
#pragma unroll
        for (int rg = 0; rg < 4; ++rg) {
            int m = w * 16 + qd * 4 + rg;
            size_t sp = sp0 + m;
#pragma unroll
            for (int nt = 0; nt < 8; ++nt) {
                int co = nt * 16 + rl;
                float v = acc2[nt][rg] + b2f(inb[sp * 128 + co]);
                outb[sp * 128 + co] = f2b(v);
            }
        }
    } else {
        __syncthreads();
#pragma unroll
        for (int rg = 0; rg < 4; ++rg) {
            int m = w * 16 + qd * 4 + rg;
            size_t sp = sp0 + m;
#pragma unroll
            for (int nt = 0; nt < 8; ++nt) {
                int co = nt * 16 + rl;
                float v = acc2[nt][rg] + b2f(inb[sp * 128 + co]);
                sZ[m * 136 + co] = f2b(fmaxf(v, 0.f));
            }
        }
        __syncthreads();

        f4v acc3[4];
#pragma unroll
        for (int nt = 0; nt < 4; ++nt) acc3[nt] = (f4v)0.f;
        s8v am2[4];
#pragma unroll
        for (int kc = 0; kc < 4; ++kc)
            am2[kc] = *(const s8v*)&sZ[(w * 16 + rl) * 136 + kc * 32 + qd * 8];
#pragma unroll
        for (int kc = 0; kc < 4; ++kc)
#pragma unroll
            for (int nt = 0; nt < 4; ++nt) {
                s8v b = *(const s8v*)(wz + (((size_t)(kc * 4 + nt)) << 9) + l * 8);
                acc3[nt] = mfma16(am2[kc], b, acc3[nt]);
            }
        const size_t zr0 = (size_t)n * 4096 + (size_t)oh * 64;
#pragma unroll
        for (int rg = 0; rg < 4; ++rg) {
            size_t row = zr0 + w * 16 + qd * 4 + rg;
#pragma unroll
            for (int nt = 0; nt < 4; ++nt) {
                int co = nt * 16 + rl;
                zout[row * 64 + co] = acc3[nt][rg] + zb[co];
            }
        }
    }
}

// ---------------------------------------------------------------------------
// conv2: k4 s2 p1, 64 -> 128. Parity-split halo, M=64. XCD swizzle.
// ---------------------------------------------------------------------------
__global__ __launch_bounds__(256)
void pconv2_k(const short* __restrict__ in, const short* __restrict__ wt,
              const float* __restrict__ bias, short* __restrict__ out)
{
    __shared__ short sA[2 * 4 * 66 * 40];
    const int tid = threadIdx.x;
    const int bx = blockIdx.x;
    const int oh = ((bx & 7) << 3) | (bx >> 3);
    const int n = blockIdx.y;
    const short* inb = in + (size_t)n * 16384 * 64;
    const int w = tid >> 6, l = tid & 63, rl = l & 15, qd = l >> 4;
    const int mh = w & 1, nh = w >> 1;

    f4v acc[2][4];
#pragma unroll
    for (int a2 = 0; a2 < 2; ++a2)
#pragma unroll
        for (int nt = 0; nt < 4; ++nt) acc[a2][nt] = (f4v)0.f;

    for (int kc = 0; kc < 2; ++kc) {
        __syncthreads();
        for (int e = tid; e < 2112; e += 256) {
            int cell = e >> 2, kcn = e & 3;
            int par = cell / 264;
            int rem = cell - par * 264;
            int hr = rem / 66, c = rem - hr * 66;
            int iw = par ? (2 * c - 1) : (2 * c);
            int ih = oh * 2 - 1 + hr;
            s8v v = (s8v)0;
            if ((unsigned)ih < 128u && (unsigned)iw < 128u)
                v = *(const s8v*)(inb + ((size_t)ih * 128 + iw) * 64 + kc * 32 + kcn * 8);
            *(s8v*)&sA[((par * 4 + hr) * 66 + c) * 40 + kcn * 8] = v;
        }
        __syncthreads();

#pragma unroll
        for (int tap = 0; tap < 16; ++tap) {
            const int kh = tap >> 2, kw = tap & 3;
            const int par = 1 - (kw & 1), cofs = kw >> 1;
            s8v af[2];
#pragma unroll
            for (int a2 = 0; a2 < 2; ++a2) {
                int ow = mh * 32 + a2 * 16 + rl;
                af[a2] = *(const s8v*)&sA[((par * 4 + kh) * 66 + ow + cofs) * 40 + qd * 8];
            }
            const short* wb = wt + (((size_t)(tap * 2 + kc) * 8 + nh * 4) << 9) + l * 8;
#pragma unroll
            for (int nt = 0; nt < 4; ++nt) {
                s8v b = *(const s8v*)(wb + ((size_t)nt << 9));
#pragma unroll
                for (int a2 = 0; a2 < 2; ++a2)
                    acc[a2][nt] = mfma16(af[a2], b, acc[a2][nt]);
            }
        }
    }

#pragma unroll
    for (int a2 = 0; a2 < 2; ++a2) {
#pragma unroll
        for (int rg = 0; rg < 4; ++rg) {
            int ow = mh * 32 + a2 * 16 + qd * 4 + rg;
            size_t row = (size_t)n * 4096 + (size_t)oh * 64 + ow;
#pragma unroll
            for (int nt = 0; nt < 4; ++nt) {
                int co = nh * 64 + nt * 16 + rl;
                float v = acc[a2][nt][rg] + bias[co];
                out[row * 128 + co] = f2b(fmaxf(v, 0.f));
            }
        }
    }
}

// ---------------------------------------------------------------------------
// ConvT1 (k4 s2 p1, 128->64): parity conv w/ halo. XCD swizzle on q2.
// ---------------------------------------------------------------------------
__global__ __launch_bounds__(256)
void pct1_k(const short* __restrict__ in, const short* __restrict__ wt,
            const float* __restrict__ bias, short* __restrict__ out)
{
    __shared__ short sA[3 * 66 * 40];
    const int tid = threadIdx.x;
    const int bx = blockIdx.x, n = blockIdx.y;
    const int k8 = bx & 7;
    const int P  = (bx >> 3) & 1;
    const int q2 = k8 * 8 + (bx >> 4);
    const int oh0 = (q2 >> 1) * 4 + (q2 & 1);
    const int p = (oh0 + 1) & 1;
    const int ihb0 = (oh0 + 1 - p) >> 1;
    const short* inb = in + (size_t)n * 4096 * 128;
    const int w = tid >> 6, l = tid & 63, rl = l & 15, qd = l >> 4;
    const int mh = w & 1, nh = w >> 1;

    f4v acc[4][2];
#pragma unroll
    for (int a4 = 0; a4 < 4; ++a4)
#pragma unroll
        for (int nt = 0; nt < 2; ++nt) acc[a4][nt] = (f4v)0.f;

    for (int kc = 0; kc < 4; ++kc) {
        __syncthreads();
        for (int e = tid; e < 792; e += 256) {
            int cell = e >> 2, kcn = e & 3;
            int hr = cell / 66, c = cell - hr * 66;
            int ih = ihb0 - 1 + hr, iw = c - 1;
            s8v v = (s8v)0;
            if ((unsigned)ih < 64u && (unsigned)iw < 64u)
                v = *(const s8v*)(inb + ((size_t)ih * 64 + iw) * 128 + kc * 32 + kcn * 8);
            *(s8v*)&sA[(hr * 66 + c) * 40 + kcn * 8] = v;
        }
        __syncthreads();

#pragma unroll
        for (int a = 0; a < 2; ++a)
#pragma unroll
        for (int b = 0; b < 2; ++b) {
            const int kh = p + 2 * a;
            const int kw = (1 - P) + 2 * b;
            const int tap = kh * 4 + kw;
            const int hrw = mh + 1 - a;
            s8v af[4];
#pragma unroll
            for (int a4 = 0; a4 < 4; ++a4)
                af[a4] = *(const s8v*)&sA[(hrw * 66 + a4 * 16 + rl + P - b + 1) * 40 + qd * 8];
            const short* wbp = wt + (((size_t)(tap * 4 + kc) * 4 + nh * 2) << 9) + l * 8;
#pragma unroll
            for (int nt = 0; nt < 2; ++nt) {
                s8v bb = *(const s8v*)(wbp + ((size_t)nt << 9));
#pragma unroll
                for (int a4 = 0; a4 < 4; ++a4)
                    acc[a4][nt] = mfma16(af[a4], bb, acc[a4][nt]);
            }
        }
    }

#pragma unroll
    for (int a4 = 0; a4 < 4; ++a4) {
#pragma unroll
        for (int rg = 0; rg < 4; ++rg) {
            int j = a4 * 16 + qd * 4 + rg;
            int oh = oh0 + 2 * mh, ow = 2 * j + P;
            size_t pb = (((size_t)n * 128 + oh) * 128 + ow) * 64;
#pragma unroll
            for (int nt = 0; nt < 2; ++nt) {
                int co = nh * 32 + nt * 16 + rl;
                float v = acc[a4][nt][rg] + bias[co];
                out[pb + co] = f2b(fmaxf(v, 0.f));
            }
        }
    }
}

// ---------------------------------------------------------------------------
// ConvT2 (known-good R8 version): one output pixel/thread, 4 taps, LDS
// weights. in NHWC bf16 (16,128,128,64) -> x_rec fp32 (16,256,256).
// ---------------------------------------------------------------------------
__global__ __launch_bounds__(256)
void convt2_k(const short* __restrict__ in, const float* __restrict__ w,
              const float* __restrict__ bias, float* __restrict__ out)
{
    __shared__ float sw[16 * 64];
    const int tid = threadIdx.x;
    for (int e = tid; e < 1024; e += 256) { int ci = e >> 4, tap = e & 15; sw[tap * 64 + ci] = w[e]; }
    __syncthreads();

    const int i = blockIdx.x * 256 + tid;
    const int n = i >> 16, s = i & 65535;
    const int oh = s >> 8, ow = s & 255;

    const int p = (oh + 1) & 1, q = (ow + 1) & 1;
    const int ihb = (oh + 1 - p) >> 1, iwb = (ow + 1 - q) >> 1;

    float acc = bias[0];
#pragma unroll
    for (int a = 0; a < 2; ++a) {
        int ih = ihb - a, kh = p + 2 * a;
        bool vr = (unsigned)ih < 128u;
#pragma unroll
        for (int b = 0; b < 2; ++b) {
            int iw = iwb - b, kw = q + 2 * b;
            if (vr && (unsigned)iw < 128u) {
                const short* ip = in + (((size_t)n * 128 + ih) * 128 + iw) * 64;
                const float* wp = &sw[(kh * 4 + kw) * 64];
#pragma unroll
                for (int c = 0; c < 64; c += 8) {
                    s8v v = *(const s8v*)(ip + c);
#pragma unroll
                    for (int j = 0; j < 8; ++j) acc += b2f(v[j]) * wp[c + j];
                }
            }
        }
    }
    out[i] = acc;
}

// ---------------------------------------------------------------------------
// VQ: MFMA distance GEMM, split-bf16, fully-coalesced; no global atomics.
// ---------------------------------------------------------------------------
__global__ __launch_bounds__(256)
void vqm_k(const float* __restrict__ z, const short* __restrict__ cbh,
           const short* __restrict__ cbl, const float* __restrict__ cbsq,
           const float* __restrict__ cb,
           float* __restrict__ quant, short* __restrict__ qb,
           int* __restrict__ idxp, float* __restrict__ errbuf)
{
    __shared__ float zs[64 * 68];
    __shared__ short scb[2][8192];
    __shared__ int sidx[64];
    __shared__ float serr[4];
    float* qc = (float*)&scb[0][0];

    const int tid = threadIdx.x;
    const int w = tid >> 6, l = tid & 63, rl = l & 15, qd = l >> 4;
    const int r0 = blockIdx.x * 64;

    for (int e = tid; e < 1024; e += 256) {
        int row = e >> 4, c4 = e & 15;
        float4 t = ((const float4*)(z + (size_t)(r0 + row) * 64))[c4];
        *(float4*)&zs[row * 68 + c4 * 4] = t;
    }
    __syncthreads();

    s8v zh[2], zl[2];
#pragma unroll
    for (int kc = 0; kc < 2; ++kc) {
        const float* zp = &zs[(w * 16 + rl) * 68 + kc * 32 + qd * 8];
        s8v hi, lo;
#pragma unroll
        for (int j = 0; j < 8; ++j) {
            float v = zp[j];
            short h = f2b(v);
            hi[j] = h;
            lo[j] = f2b(v - b2f(h));
        }
        zh[kc] = hi; zl[kc] = lo;
    }

    float best[4]; int bidx[4];
#pragma unroll
    for (int rg = 0; rg < 4; ++rg) { best[rg] = 3.4e38f; bidx[rg] = 0; }

    for (int ch = 0; ch < 4; ++ch) {
        __syncthreads();
        for (int e = tid; e < 1024; e += 256) {
            int kcL = e >> 9, rest = e & 511;
            int ntl = rest >> 6, off = rest & 63;
            int srcIdx = (kcL * 32 + ch * 8 + ntl) * 64 + off;
            *(s8v*)&scb[0][e * 8] = ((const s8v*)cbh)[srcIdx];
            *(s8v*)&scb[1][e * 8] = ((const s8v*)cbl)[srcIdx];
        }
        __syncthreads();

        float sq[8];
#pragma unroll
        for (int nt = 0; nt < 8; ++nt) sq[nt] = cbsq[ch * 128 + nt * 16 + rl];

        f4v acc[8];
#pragma unroll
        for (int nt = 0; nt < 8; ++nt) acc[nt] = (f4v)0.f;
#pragma unroll
        for (int kc = 0; kc < 2; ++kc) {
#pragma unroll
            for (int nt = 0; nt < 8; ++nt) {
                s8v bh = *(const s8v*)&scb[0][(kc * 8 + nt) * 512 + l * 8];
                s8v bl = *(const s8v*)&scb[1][(kc * 8 + nt) * 512 + l * 8];
                acc[nt] = mfma16(zh[kc], bh, acc[nt]);
                acc[nt] = mfma16(zh[kc], bl, acc[nt]);
                acc[nt] = mfma16(zl[kc], bh, acc[nt]);
            }
        }

#pragma unroll
        for (int rg = 0; rg < 4; ++rg) {
            float bd = best[rg]; int bi = bidx[rg];
#pragma unroll
            for (int nt = 0; nt < 8; ++nt) {
                float d = sq[nt] - 2.f * acc[nt][rg];
                int code = ch * 128 + nt * 16 + rl;
                if (d < bd) { bd = d; bi = code; }
            }
            best[rg] = bd; bidx[rg] = bi;
        }
    }

#pragma unroll
    for (int rg = 0; rg < 4; ++rg) {
        float bd = best[rg]; int bi = bidx[rg];
#pragma unroll
        for (int off = 1; off < 16; off <<= 1) {
            float od = __shfl_xor(bd, off, 64);
            int   oi = __shfl_xor(bi, off, 64);
            if (od < bd || (od == bd && oi < bi)) { bd = od; bi = oi; }
        }
        if (rl == 0) sidx[w * 16 + qd * 4 + rg] = bi;
    }
    __syncthreads();

    const int n = r0 >> 12, s0 = r0 & 4095;
    float err = 0.f;
#pragma unroll 4
    for (int i = 0; i < 16; ++i) {
        int rr = w * 16 + i;
        int bi = sidx[rr];
        float c = cb[(size_t)bi * 64 + l];
        float zv = zs[rr * 68 + l];
        float dd = zv - c;
        err += dd * dd;
        qb[(size_t)(r0 + rr) * 64 + l] = f2b(c);
        qc[l * 68 + rr] = c;
    }
#pragma unroll
    for (int o = 32; o; o >>= 1) err += __shfl_down(err, o, 64);
    if (l == 0) serr[w] = err;
    if (tid < 64) idxp[r0 + tid] = sidx[tid];
    __syncthreads();

#pragma unroll 4
    for (int dd = 0; dd < 16; ++dd) {
        int d = w * 16 + dd;
        quant[((size_t)(n * 64 + d)) * 4096 + s0 + l] = qc[d * 68 + l];
    }
    if (tid == 0) errbuf[blockIdx.x] = serr[0] + serr[1] + serr[2] + serr[3];
}

__global__ __launch_bounds__(1024)
void fin_k(const int* __restrict__ idxp, const float* __restrict__ errbuf,
           float* out_loss, float* out_perp)
{
    __shared__ int lc[512];
    __shared__ float red[1024];
    const int t = threadIdx.x;
    if (t < 512) lc[t] = 0;
    __syncthreads();
    for (int i = t; i < 65536; i += 1024) atomicAdd(&lc[idxp[i]], 1);
    __syncthreads();
    float v = 0.f;
    if (t < 512) {
        float avg = (float)lc[t] * (1.0f / 65536.0f);
        v = avg * logf(avg + 1e-10f);
    }
    red[t] = v;
    __syncthreads();
    for (int st = 512; st; st >>= 1) { if (t < st) red[t] += red[t + st]; __syncthreads(); }
    if (t == 0) *out_perp = expf(-red[0]);
    __syncthreads();
    red[t] = errbuf[t];
    __syncthreads();
    for (int st = 512; st; st >>= 1) { if (t < st) red[t] += red[t + st]; __syncthreads(); }
    if (t == 0) *out_loss = red[0] * (1.25f / 4194304.0f);
}

__global__ __launch_bounds__(256)
void enc_k(const int* __restrict__ idxp, float4* __restrict__ enc)
{
    int i = blockIdx.x * 256 + threadIdx.x;
    int r = i >> 7, c4 = (i & 127) * 4;
    int k = idxp[r];
    float4 v;
    v.x = (k == c4)     ? 1.f : 0.f;
    v.y = (k == c4 + 1) ? 1.f : 0.f;
    v.z = (k == c4 + 2) ? 1.f : 0.f;
    v.w = (k == c4 + 3) ? 1.f : 0.f;
    enc[i] = v;
}

// ---------------------------------------------------------------------------
extern "C" void kernel_launch(void* const* d_in, const int* in_sizes, int n_in,
                              void* d_out, int out_size, void* d_ws, size_t ws_size,
                              hipStream_t stream)
{
    const float* x    = (const float*)d_in[0];
    const float* ew1  = (const float*)d_in[1];
    const float* eb1  = (const float*)d_in[2];
    const float* ew2  = (const float*)d_in[3];
    const float* eb2  = (const float*)d_in[4];
    const float* ew3  = (const float*)d_in[5];
    const float* eb3  = (const float*)d_in[6];
    const float* er1a = (const float*)d_in[7];
    const float* er1b = (const float*)d_in[8];
    const float* er2a = (const float*)d_in[9];
    const float* er2b = (const float*)d_in[10];
    const float* pw   = (const float*)d_in[11];
    const float* pb   = (const float*)d_in[12];
    const float* cb   = (const float*)d_in[13];
    const float* dw1w = (const float*)d_in[14];
    const float* db1  = (const float*)d_in[15];
    const float* dr1a = (const float*)d_in[16];
    const float* dr1b = (const float*)d_in[17];
    const float* dr2a = (const float*)d_in[18];
    const float* dr2b = (const float*)d_in[19];
    const float* dtw1 = (const float*)d_in[20];
    const float* dtb1 = (const float*)d_in[21];
    const float* dtw2 = (const float*)d_in[22];
    const float* dtb2 = (const float*)d_in[23];

    char* wsb = (char*)d_ws;
    short* wbase = (short*)wsb;
    short* wt2   = wbase;
    short* wt3   = wbase + 131072;
    short* wr1a  = wbase + 278528;
    short* wr1b  = wbase + 315392;
    short* wr2a  = wbase + 319488;
    short* wr2b  = wbase + 356352;
    short* wpwt  = wbase + 360448;
    short* wd1   = wbase + 368640;
    short* wdr1a = wbase + 442368;
    short* wdr1b = wbase + 479232;
    short* wdr2a = wbase + 483328;
    short* wdr2b = wbase + 520192;
    short* wtt1  = wbase + 524288;

    short* h2   = (short*)(wsb + 1310720);
    short* buf  = (short*)(wsb + 18087936);
    short* qb   = (short*)(wsb + 39059456);
    float* z    = (float*)(wsb + 47448064);
    int*   idx  = (int*)  (wsb + 64225280);
    if (ws_size < (size_t)64489480) return;

    float* out    = (float*)d_out;
    float* o_loss = out;
    float* xrec   = out + 1;
    float* o_perp = out + 1048577;
    float* enc    = out + 1048578;
    float* quant  = out + 34603010;
    char*  encB = (char*)d_out + (size_t)1048580 * 4;
    short* h1  = (short*)encB;
    short* dt1 = h1 + 16777216;
    short* cbh  = (short*)(encB + ((size_t)120 << 20));
    short* cbl  = cbh + 32768;
    float* cbsq = (float*)(cbl + 32768);
    float* errbuf = (float*)(encB + ((size_t)121 << 20));

    WtArgs wa;
    wa.d[0]  = { ew2,  128,  64, 16, 0, 0      };
    wa.d[1]  = { ew3,  128, 128,  9, 0, 131072 };
    wa.d[2]  = { er1a,  32, 128,  9, 0, 278528 };
    wa.d[3]  = { er1b, 128,  32,  1, 0, 315392 };
    wa.d[4]  = { er2a,  32, 128,  9, 0, 319488 };
    wa.d[5]  = { er2b, 128,  32,  1, 0, 356352 };
    wa.d[6]  = { pw,    64, 128,  1, 0, 360448 };
    wa.d[7]  = { dw1w, 128,  64,  9, 0, 368640 };
    wa.d[8]  = { dr1a,  32, 128,  9, 0, 442368 };
    wa.d[9]  = { dr1b, 128,  32,  1, 0, 479232 };
    wa.d[10] = { dr2a,  32, 128,  9, 0, 483328 };
    wa.d[11] = { dr2b, 128,  32,  1, 0, 520192 };
    wa.d[12] = { dtw1,  64, 128, 16, 1, 524288 };
    wa.total = 655360;
    prep_k<<<dim3(2562), TPB, 0, stream>>>(wa, wbase, cb, cbh, cbl, cbsq);

    // ---- encoder ----
    conv1_k<<<dim3(128, 16), TPB, 0, stream>>>(x, ew1, eb1, h1);
    pconv2_k<<<dim3(64, 16), TPB, 0, stream>>>(h1, wt2, eb2, h2);
    pconv3s_k<128,128,false,false,false><<<dim3(64,16), TPB, 0, stream>>>(h2, wt3, eb3, buf);
    rfuse_k<0><<<dim3(64,16), TPB, 0, stream>>>(buf, wr1a, wr1b, h2, nullptr, nullptr, nullptr);
    rfuse_k<1><<<dim3(64,16), TPB, 0, stream>>>(h2,  wr2a, wr2b, nullptr, wpwt, pb, z);

    // ---- VQ ----
    vqm_k<<<dim3(1024), TPB, 0, stream>>>(z, cbh, cbl, cbsq, cb, quant, qb, idx, errbuf);
    fin_k<<<dim3(1), 1024, 0, stream>>>(idx, errbuf, o_loss, o_perp);

    // ---- decoder ----
    pconv3s_k< 64,128,false,false,false><<<dim3(64,16), TPB, 0, stream>>>(qb, wd1, db1, buf);
    rfuse_k<0><<<dim3(64,16), TPB, 0, stream>>>(buf, wdr1a, wdr1b, h2, nullptr, nullptr, nullptr);
    rfuse_k<0><<<dim3(64,16), TPB, 0, stream>>>(h2,  wdr2a, wdr2b, buf, nullptr, nullptr, nullptr);
    pct1_k<<<dim3(128, 16), TPB, 0, stream>>>(buf, wtt1, dtb1, dt1);
    convt2_k<<<dim3(4096), TPB, 0, stream>>>(dt1, dtw2, dtb2, xrec);

    // ---- encodings (last) ----
    enc_k<<<dim3(32768), TPB, 0, stream>>>(idx, (float4*)enc);
}